// Round 4
// baseline (255.116 us; speedup 1.0000x reference)
//
#include <hip/hip_runtime.h>

typedef unsigned short ushort_t;
typedef unsigned int uint_t;
typedef __attribute__((ext_vector_type(4))) float f32x4;
typedef __attribute__((ext_vector_type(8))) short bf16x8;

#define B_   16
#define T_   2048
#define H_   1024
#define G_   2
#define V_   320
#define D_   128
#define NT   32768   // B*T
#define GV   640     // G*V
#define GD   256     // G*D

#define LGKM0() asm volatile("s_waitcnt lgkmcnt(0)" ::: "memory")
#define BAR()   __builtin_amdgcn_s_barrier()
#define GLDS16(g, l) __builtin_amdgcn_global_load_lds( \
    (const __attribute__((address_space(1))) void*)(g), \
    (__attribute__((address_space(3))) void*)(l), 16, 0, 0)

__device__ __forceinline__ ushort_t cvt_bf16(float f) {
  uint_t u = __float_as_uint(f);
  uint_t r = (u + 0x7FFFu + ((u >> 16) & 1u)) >> 16;
  return (ushort_t)r;
}

__device__ __forceinline__ bf16x8 pack8(f32x4 a, f32x4 b) {
  union { uint_t u[4]; bf16x8 v; } r;
  asm("v_cvt_pk_bf16_f32 %0, %1, %2" : "=v"(r.u[0]) : "v"(a[0]), "v"(a[1]));
  asm("v_cvt_pk_bf16_f32 %0, %1, %2" : "=v"(r.u[1]) : "v"(a[2]), "v"(a[3]));
  asm("v_cvt_pk_bf16_f32 %0, %1, %2" : "=v"(r.u[2]) : "v"(b[0]), "v"(b[1]));
  asm("v_cvt_pk_bf16_f32 %0, %1, %2" : "=v"(r.u[3]) : "v"(b[2]), "v"(b[3]));
  return r.v;
}

// ---------------- prep: convert weights to bf16, pack codebook frags, zero accums ----------------
__global__ void pq_prep(const float* __restrict__ W_in, const float* __restrict__ W_out,
                        const float* __restrict__ cb, ushort_t* __restrict__ winb,
                        ushort_t* __restrict__ woutb, ushort_t* __restrict__ cbp,
                        float* __restrict__ avg_g, float* __restrict__ closs,
                        uint_t* __restrict__ counter) {
  int idx = blockIdx.x * 256 + threadIdx.x;
  const int N1 = GV * H_;    // 655360
  const int N2 = H_ * GD;    // 262144
  const int N3 = 81920;      // G * 10 * 8 * 64 * 8
  if (idx < N1) { winb[idx] = cvt_bf16(W_in[idx]); return; }
  idx -= N1;
  if (idx < N2) { woutb[idx] = cvt_bf16(W_out[idx]); return; }
  idx -= N2;
  if (idx < N3) {
    int g = idx / 40960;
    int r = idx % 40960;
    int kk = r / 4096;
    int r2 = r % 4096;
    int n  = r2 >> 9;
    int ln = (r2 >> 3) & 63;
    int i  = r2 & 7;
    int v = kk * 32 + (ln >> 4) * 8 + i;   // k index (codebook row)
    int d = n * 16 + (ln & 15);            // col index
    cbp[idx] = cvt_bf16(cb[((size_t)g * V_ + v) * D_ + d]);
    return;
  }
  idx -= N3;
  if (idx < GV) { avg_g[idx] = 0.f; return; }
  idx -= GV;
  if (idx == 0) { *closs = 0.f; *counter = 0u; }
}

// ---------------- kernel A: logits GEMM + gumbel softmax + avg_probs + probs@codebook ----------------
// GEMM1: A fragments loaded DIRECTLY from x (coalesced 16 rows x 128 B per instr, reg prefetch 1 deep);
// B staged via global_load_lds into 3 rotating LDS buffers (2-iteration prefetch depth, vmcnt(5) steady).
__global__ __launch_bounds__(512, 2) void pq_kA(
    const float* __restrict__ x, const float* __restrict__ b_in,
    const float* __restrict__ gum, const ushort_t* __restrict__ winb,
    const ushort_t* __restrict__ cbp, ushort_t* __restrict__ qmid,
    float* __restrict__ avg_g) {
  __shared__ char smem[125440];
  char* sBbuf = smem;                      // [3][40960] bf16 B tiles (src-swizzled, linear dest)
  char* sP    = smem;                      // probs [64][640] bf16 swizzled (epilogue union, 80 KB)
  float* sAvg = (float*)(smem + 122880);   // [640]

  const int tid = threadIdx.x;
  const int lane = tid & 63;
  const int wid = tid >> 6;    // 0..7
  const int wm = wid >> 1;     // 0..3  (M wave)
  const int g  = wid & 1;      // group
  const int lo = lane & 15;
  const int hi = lane >> 4;
  const int row0 = blockIdx.x * 128;

  for (int i = tid; i < GV; i += 512) sAvg[i] = 0.f;

  // B DMA source (pre-swizzled so linear LDS dest => conflict-free frag reads), as round 3
  const int bV   = wid * 80 + (lane >> 2);
  const int bCc  = (lane & 3) ^ ((lane >> 3) & 3);
  const ushort_t* bSrc0 = winb + (size_t)bV * H_ + bCc * 8;

  // A direct-from-global pointers: wave wm covers rows wm*32 + lo (+16); k chunk = hi*8
  const float* xr0 = x + (size_t)(row0 + wm * 32 + lo) * H_ + hi * 8;
  const float* xr1 = xr0 + (size_t)16 * H_;

  f32x4 acc[2][20];
#pragma unroll
  for (int m = 0; m < 2; ++m)
#pragma unroll
    for (int n = 0; n < 20; ++n) acc[m][n] = (f32x4){0.f, 0.f, 0.f, 0.f};

  __syncthreads();

#define STAGEB(buf, kb)                                                         \
  do {                                                                          \
    char* lb = sBbuf + (buf) * 40960 + wid * 5120;                              \
    const ushort_t* bs = bSrc0 + (kb);                                          \
    GLDS16(bs,             lb);                                                 \
    GLDS16(bs + 16 * H_,   lb + 1024);                                          \
    GLDS16(bs + 32 * H_,   lb + 2048);                                          \
    GLDS16(bs + 48 * H_,   lb + 3072);                                          \
    GLDS16(bs + 64 * H_,   lb + 4096);                                          \
  } while (0)

  // prologue: B(0), x(0), B(1)   -> queue [B0(5), x0(4), B1(5)]
  STAGEB(0, 0);
  f32x4 xa0 = *reinterpret_cast<const f32x4*>(xr0);
  f32x4 xa1 = *reinterpret_cast<const f32x4*>(xr0 + 4);
  f32x4 xb0 = *reinterpret_cast<const f32x4*>(xr1);
  f32x4 xb1 = *reinterpret_cast<const f32x4*>(xr1 + 4);
  STAGEB(1, 32);

  const int swzB = (lo >> 1) & 3;

  // ---- GEMM1: logits[128][640] = x_tile[128][1024] @ W_in^T ----
#pragma unroll 1
  for (int ks = 0; ks < 32; ++ks) {
    // steady state: complete B(ks)+x(ks), leave B(ks+1) (5) in flight
    if (ks < 31) asm volatile("s_waitcnt vmcnt(5)" ::: "memory");
    else         asm volatile("s_waitcnt vmcnt(0)" ::: "memory");
    BAR();

    bf16x8 af0 = pack8(xa0, xa1);
    bf16x8 af1 = pack8(xb0, xb1);

    // issue next-step loads AFTER cvt freed the x regs; they cover until next iter's wait
    if (ks < 31) {
      const int ko = (ks + 1) * 32;
      xa0 = *reinterpret_cast<const f32x4*>(xr0 + ko);
      xa1 = *reinterpret_cast<const f32x4*>(xr0 + ko + 4);
      xb0 = *reinterpret_cast<const f32x4*>(xr1 + ko);
      xb1 = *reinterpret_cast<const f32x4*>(xr1 + ko + 4);
      if (ks < 30) STAGEB((ks + 2) % 3, (ks + 2) * 32);
    }

    const char* cB = sBbuf + (ks % 3) * 40960;
#pragma unroll
    for (int n = 0; n < 20; ++n) {
      const int v = g * 320 + n * 16 + lo;
      bf16x8 bf = *reinterpret_cast<const bf16x8*>(cB + v * 64 + ((hi ^ swzB) * 16));
      acc[0][n] = __builtin_amdgcn_mfma_f32_16x16x32_bf16(af0, bf, acc[0][n], 0, 0, 0);
      acc[1][n] = __builtin_amdgcn_mfma_f32_16x16x32_bf16(af1, bf, acc[1][n], 0, 0, 0);
    }
    LGKM0();   // my frag reads drained -> buffer safe to overwrite 2 iters later
    BAR();
  }
#undef STAGEB

  // ---- epilogue: gumbel softmax (wave-local rows), avg_probs, GEMM2 ----
  float bias[20];
#pragma unroll
  for (int n = 0; n < 20; ++n) bias[n] = b_in[g * 320 + n * 16 + lo];

#pragma unroll
  for (int mrep = 0; mrep < 2; ++mrep) {
#pragma unroll
    for (int j = 0; j < 4; ++j) {
      const int trow = row0 + wm * 32 + mrep * 16 + hi * 4 + j;
      const float* up = gum + ((size_t)trow * G_ + g) * V_;
      float zmax = -3.0e38f;
#pragma unroll
      for (int n = 0; n < 20; ++n) {
        float u = up[n * 16 + lo];
        float gv = -__logf(-__logf(u));
        float z = acc[mrep][n][j] + bias[n] + gv;
        acc[mrep][n][j] = z;
        zmax = fmaxf(zmax, z);
      }
#pragma unroll
      for (int mk = 1; mk <= 8; mk <<= 1) zmax = fmaxf(zmax, __shfl_xor(zmax, mk));
      float s = 0.f;
#pragma unroll
      for (int n = 0; n < 20; ++n) {
        float p = __expf(acc[mrep][n][j] - zmax);
        acc[mrep][n][j] = p;
        s += p;
      }
#pragma unroll
      for (int mk = 1; mk <= 8; mk <<= 1) s += __shfl_xor(s, mk);
      float inv = 1.f / s;
#pragma unroll
      for (int n = 0; n < 20; ++n) acc[mrep][n][j] *= inv;
    }
    // avg_probs accumulation (sum over this wave's 16 rows)
#pragma unroll
    for (int n = 0; n < 20; ++n) {
      float cs = acc[mrep][n][0] + acc[mrep][n][1] + acc[mrep][n][2] + acc[mrep][n][3];
      cs += __shfl_xor(cs, 16);
      cs += __shfl_xor(cs, 32);
      if (hi == 0) atomicAdd(&sAvg[g * 320 + n * 16 + lo], cs);
    }
    // probs -> LDS bf16 (pair-packed, wave-local region)
#pragma unroll
    for (int n = 0; n < 20; ++n) {
#pragma unroll
      for (int j = 0; j < 4; ++j) {
        float v = acc[mrep][n][j];
        float pv = __shfl_xor(v, 1);
        if ((lane & 1) == 0) {
          uint_t w = (uint_t)cvt_bf16(v) | ((uint_t)cvt_bf16(pv) << 16);
          int prow = wm * 16 + hi * 4 + j;
          int byte = (prow * 1280 + (g * 320 + n * 16 + lo) * 2) ^ ((prow & 7) << 4);
          *reinterpret_cast<uint_t*>(sP + byte) = w;
        }
      }
    }
    LGKM0();
    // GEMM2: qmid[16][128] = P[16][320] @ codebook[g]  (wave reads only its own writes)
    f32x4 acc2[8];
#pragma unroll
    for (int n = 0; n < 8; ++n) acc2[n] = (f32x4){0.f, 0.f, 0.f, 0.f};
#pragma unroll
    for (int kk = 0; kk < 10; ++kk) {
      int prow = wm * 16 + lo;
      int byte = (prow * 1280 + g * 640 + kk * 64 + hi * 16) ^ ((prow & 7) << 4);
      bf16x8 ap = *reinterpret_cast<const bf16x8*>(sP + byte);
#pragma unroll
      for (int n = 0; n < 8; ++n) {
        bf16x8 bc = *reinterpret_cast<const bf16x8*>(cbp + ((size_t)((g * 10 + kk) * 8 + n) * 64 + lane) * 8);
        acc2[n] = __builtin_amdgcn_mfma_f32_16x16x32_bf16(ap, bc, acc2[n], 0, 0, 0);
      }
    }
    // write qmid bf16 (pair-packed u32 stores)
#pragma unroll
    for (int n = 0; n < 8; ++n) {
#pragma unroll
      for (int j = 0; j < 4; ++j) {
        float v = acc2[n][j];
        float pv = __shfl_xor(v, 1);
        if ((lane & 1) == 0) {
          uint_t w = (uint_t)cvt_bf16(v) | ((uint_t)cvt_bf16(pv) << 16);
          int trow = row0 + wm * 32 + mrep * 16 + hi * 4 + j;
          *reinterpret_cast<uint_t*>(qmid + (size_t)trow * GD + g * 128 + n * 16 + lo) = w;
        }
      }
    }
  }
  __syncthreads();
  for (int i = tid; i < GV; i += 512) atomicAdd(&avg_g[i], sAvg[i]);
}

// ---------------- kernel B: q = qmid @ W_out^T + b_out, commit loss, fused finalize ----------------
__global__ __launch_bounds__(512, 2) void pq_kB(
    const ushort_t* __restrict__ qmid, const ushort_t* __restrict__ woutb,
    const float* __restrict__ b_out, const float* __restrict__ x,
    float* __restrict__ out, float* __restrict__ closs,
    const float* __restrict__ avg_g, uint_t* __restrict__ counter) {
  __shared__ char smem[49152 + 64];
  __shared__ int sLast;
  char* sA = smem;            // [128][64] bf16 swizzled
  char* sB = smem + 16384;    // [256][64] bf16 swizzled
  float* sRed = (float*)(smem + 49152);

  const int tid = threadIdx.x;
  const int lane = tid & 63;
  const int wid = tid >> 6;
  const int wm = wid >> 2;    // 0..1
  const int wn = wid & 3;     // 0..3
  const int lo = lane & 15, hi = lane >> 4;
  const int tm = blockIdx.x >> 2;
  const int tn = blockIdx.x & 3;
  const int row0 = tm * 128;
  const int col0 = tn * 256;

  f32x4 acc[4][4];
#pragma unroll
  for (int mr = 0; mr < 4; ++mr)
#pragma unroll
    for (int nr = 0; nr < 4; ++nr) acc[mr][nr] = (f32x4){0.f, 0.f, 0.f, 0.f};

  for (int ks = 0; ks < 4; ++ks) {
    const int kb = ks * 64;
#pragma unroll
    for (int u = 0; u < 2; ++u) {
      int s = u * 512 + tid;
      int r = s >> 3, c = s & 7;
      uint4 wv = *reinterpret_cast<const uint4*>(qmid + (size_t)(row0 + r) * GD + kb + c * 8);
      int byte = (r * 128 + c * 16) ^ ((r & 7) << 4);
      *reinterpret_cast<uint4*>(sA + byte) = wv;
    }
#pragma unroll
    for (int u = 0; u < 4; ++u) {
      int s = u * 512 + tid;
      int r = s >> 3, c = s & 7;
      uint4 wv = *reinterpret_cast<const uint4*>(woutb + (size_t)(col0 + r) * GD + kb + c * 8);
      int byte = (r * 128 + c * 16) ^ ((r & 7) << 4);
      *reinterpret_cast<uint4*>(sB + byte) = wv;
    }
    __syncthreads();
#pragma unroll
    for (int kk = 0; kk < 2; ++kk) {
      bf16x8 af[4], bf[4];
#pragma unroll
      for (int mr = 0; mr < 4; ++mr) {
        int row = wm * 64 + mr * 16 + lo;
        int byte = (row * 128 + kk * 64 + hi * 16) ^ ((row & 7) << 4);
        af[mr] = *reinterpret_cast<const bf16x8*>(sA + byte);
      }
#pragma unroll
      for (int nr = 0; nr < 4; ++nr) {
        int col = wn * 64 + nr * 16 + lo;
        int byte = (col * 128 + kk * 64 + hi * 16) ^ ((col & 7) << 4);
        bf[nr] = *reinterpret_cast<const bf16x8*>(sB + byte);
      }
#pragma unroll
      for (int mr = 0; mr < 4; ++mr)
#pragma unroll
        for (int nr = 0; nr < 4; ++nr)
          acc[mr][nr] = __builtin_amdgcn_mfma_f32_16x16x32_bf16(af[mr], bf[nr], acc[mr][nr], 0, 0, 0);
    }
    __syncthreads();
  }
  // epilogue: bias, store q, commit loss
  float bias[4];
#pragma unroll
  for (int nr = 0; nr < 4; ++nr) bias[nr] = b_out[col0 + wn * 64 + nr * 16 + lo];
  float csum = 0.f;
#pragma unroll
  for (int mr = 0; mr < 4; ++mr)
#pragma unroll
    for (int nr = 0; nr < 4; ++nr)
#pragma unroll
      for (int j = 0; j < 4; ++j) {
        int row = row0 + wm * 64 + mr * 16 + hi * 4 + j;
        int col = col0 + wn * 64 + nr * 16 + lo;
        float q = acc[mr][nr][j] + bias[nr];
        out[(size_t)row * H_ + col] = q;
        float d = x[(size_t)row * H_ + col] - q;
        csum += d * d;
      }
#pragma unroll
  for (int mk = 1; mk <= 32; mk <<= 1) csum += __shfl_xor(csum, mk);
  if (lane == 0) sRed[wid] = csum;
  __syncthreads();
  if (tid == 0) {
    float t = 0.f;
    for (int w = 0; w < 8; ++w) t += sRed[w];
    atomicAdd(closs, t);
    __threadfence();
    uint_t c = atomicAdd(counter, 1u);
    sLast = (c == 1023u) ? 1 : 0;
  }
  __syncthreads();
  // last block finalizes perplexity + commit loss
  if (sLast && tid < 64) {
    float a0 = 0.f, a1 = 0.f;
    for (int v = tid; v < V_; v += 64) {
      float p0 = avg_g[v] * (1.f / (float)NT);
      a0 += p0 * __logf(p0 + 1e-9f);
      float p1 = avg_g[V_ + v] * (1.f / (float)NT);
      a1 += p1 * __logf(p1 + 1e-9f);
    }
#pragma unroll
    for (int mk = 1; mk <= 32; mk <<= 1) { a0 += __shfl_xor(a0, mk); a1 += __shfl_xor(a1, mk); }
    if (tid == 0) {
      float cl = atomicAdd(closs, 0.0f);   // coherent read of accumulated value
      out[(size_t)NT * H_]     = 0.5f * (__expf(-a0) + __expf(-a1));
      out[(size_t)NT * H_ + 1] = cl * (1.f / ((float)NT * (float)H_));
    }
  }
}

extern "C" void kernel_launch(void* const* d_in, const int* in_sizes, int n_in,
                              void* d_out, int out_size, void* d_ws, size_t ws_size,
                              hipStream_t stream) {
  const float* x     = (const float*)d_in[0];
  const float* W_in  = (const float*)d_in[1];
  const float* b_in  = (const float*)d_in[2];
  const float* cb    = (const float*)d_in[3];
  const float* W_out = (const float*)d_in[4];
  const float* b_out = (const float*)d_in[5];
  const float* gum   = (const float*)d_in[6];
  float* out = (float*)d_out;

  char* ws = (char*)d_ws;
  ushort_t* winb  = (ushort_t*)ws;                 // 640*1024*2   = 1,310,720 B
  ushort_t* woutb = (ushort_t*)(ws + 1310720);     // 1024*256*2   =   524,288 B
  ushort_t* cbp   = (ushort_t*)(ws + 1835008);     // 81920*2      =   163,840 B
  float*    avg_g = (float*)(ws + 1998848);        // 640*4        =     2,560 B
  float*    closs = (float*)(ws + 2001408);        // 4 B
  uint_t*   cnt   = (uint_t*)(ws + 2001472);       // 4 B
  ushort_t* qmid  = (ushort_t*)(ws + 2001920);     // 32768*256*2  = 16,777,216 B

  pq_prep<<<3907, 256, 0, stream>>>(W_in, W_out, cb, winb, woutb, cbp, avg_g, closs, cnt);
  pq_kA<<<256, 512, 0, stream>>>(x, b_in, gum, winb, cbp, qmid, avg_g);
  pq_kB<<<1024, 512, 0, stream>>>(qmid, woutb, b_out, x, out, closs, avg_g, cnt);
}

// Round 5
// 245.126 us; speedup vs baseline: 1.0408x; 1.0408x over previous
//
#include <hip/hip_runtime.h>

typedef unsigned short ushort_t;
typedef unsigned int uint_t;
typedef __attribute__((ext_vector_type(4))) float f32x4;
typedef __attribute__((ext_vector_type(8))) short bf16x8;

#define B_   16
#define T_   2048
#define H_   1024
#define G_   2
#define V_   320
#define D_   128
#define NT   32768   // B*T
#define GV   640     // G*V
#define GD   256     // G*D

#define LGKM0() asm volatile("s_waitcnt lgkmcnt(0)" ::: "memory")
#define BAR()   __builtin_amdgcn_s_barrier()
#define GLDS16(g, l) __builtin_amdgcn_global_load_lds( \
    (const __attribute__((address_space(1))) void*)(g), \
    (__attribute__((address_space(3))) void*)(l), 16, 0, 0)

__device__ __forceinline__ ushort_t cvt_bf16(float f) {
  uint_t u = __float_as_uint(f);
  uint_t r = (u + 0x7FFFu + ((u >> 16) & 1u)) >> 16;
  return (ushort_t)r;
}

__device__ __forceinline__ bf16x8 pack8(f32x4 a, f32x4 b) {
  union { uint_t u[4]; bf16x8 v; } r;
  asm("v_cvt_pk_bf16_f32 %0, %1, %2" : "=v"(r.u[0]) : "v"(a[0]), "v"(a[1]));
  asm("v_cvt_pk_bf16_f32 %0, %1, %2" : "=v"(r.u[1]) : "v"(a[2]), "v"(a[3]));
  asm("v_cvt_pk_bf16_f32 %0, %1, %2" : "=v"(r.u[2]) : "v"(b[0]), "v"(b[1]));
  asm("v_cvt_pk_bf16_f32 %0, %1, %2" : "=v"(r.u[3]) : "v"(b[2]), "v"(b[3]));
  return r.v;
}

// ---------------- prep: convert weights to bf16, pack codebook frags, zero accums ----------------
__global__ void pq_prep(const float* __restrict__ W_in, const float* __restrict__ W_out,
                        const float* __restrict__ cb, ushort_t* __restrict__ winb,
                        ushort_t* __restrict__ woutb, ushort_t* __restrict__ cbp,
                        float* __restrict__ avg_g, float* __restrict__ closs,
                        uint_t* __restrict__ counter) {
  int idx = blockIdx.x * 256 + threadIdx.x;
  const int N1 = GV * H_;    // 655360
  const int N2 = H_ * GD;    // 262144
  const int N3 = 81920;      // G * 10 * 8 * 64 * 8
  if (idx < N1) { winb[idx] = cvt_bf16(W_in[idx]); return; }
  idx -= N1;
  if (idx < N2) { woutb[idx] = cvt_bf16(W_out[idx]); return; }
  idx -= N2;
  if (idx < N3) {
    int g = idx / 40960;
    int r = idx % 40960;
    int kk = r / 4096;
    int r2 = r % 4096;
    int n  = r2 >> 9;
    int ln = (r2 >> 3) & 63;
    int i  = r2 & 7;
    int v = kk * 32 + (ln >> 4) * 8 + i;   // k index (codebook row)
    int d = n * 16 + (ln & 15);            // col index
    cbp[idx] = cvt_bf16(cb[((size_t)g * V_ + v) * D_ + d]);
    return;
  }
  idx -= N3;
  if (idx < GV) { avg_g[idx] = 0.f; return; }
  idx -= GV;
  if (idx == 0) { *closs = 0.f; *counter = 0u; }
}

// ---------------- kernel A: logits GEMM + gumbel softmax + avg_probs + probs@codebook ----------------
// Grid 512 = 256 row-tiles x 2 groups; 256 threads (4 waves), each wave M=32 rows, N=320 (one group).
// LDS 42.2 KB -> 2 blocks/CU (cross-block TLP hides DMA/global latency).
// B staged via global_load_lds (pre-swizzled source), 2 buffers, staged at iter top (1-iter cover).
// A (x) loaded direct-to-register, 1-step prefetch, converted via v_cvt_pk_bf16_f32.
__global__ __launch_bounds__(256, 2) void pq_kA(
    const float* __restrict__ x, const float* __restrict__ b_in,
    const float* __restrict__ gum, const ushort_t* __restrict__ winb,
    const ushort_t* __restrict__ cbp, ushort_t* __restrict__ qmid,
    float* __restrict__ avg_g) {
  __shared__ char smem[43520];
  char* sBbuf = smem;                      // [2][20480] bf16 B tiles (src-swizzled, linear dest)
  char* sP    = smem;                      // probs [64][320] bf16 swizzled, 640B rows (epilogue union)
  float* sAvg = (float*)(smem + 40960);    // [320]

  const int tid = threadIdx.x;
  const int lane = tid & 63;
  const int wid = tid >> 6;    // 0..3
  const int wm = wid;          // M wave
  const int g  = blockIdx.x & 1;
  const int lo = lane & 15;
  const int hi = lane >> 4;
  const int row0 = (blockIdx.x >> 1) * 128;

  for (int i = tid; i < V_; i += 256) sAvg[i] = 0.f;

  // B DMA source (pre-swizzled: chunk cc = (lane&3) ^ ((lane>>3)&3) so linear LDS dest
  // => conflict-free b128 frag reads with swzB = (lo>>1)&3)
  const int bV   = wid * 80 + (lane >> 2);          // tile row 0..319 (with +u*16)
  const int bCc  = (lane & 3) ^ ((lane >> 3) & 3);
  const ushort_t* bSrc0 = winb + (size_t)(g * 320 + bV) * H_ + bCc * 8;

  // A direct-from-global: wave wm covers rows wm*32 + lo (+16); k chunk = hi*8
  const float* xr0 = x + (size_t)(row0 + wm * 32 + lo) * H_ + hi * 8;
  const float* xr1 = xr0 + (size_t)16 * H_;

  f32x4 acc[2][20];
#pragma unroll
  for (int m = 0; m < 2; ++m)
#pragma unroll
    for (int n = 0; n < 20; ++n) acc[m][n] = (f32x4){0.f, 0.f, 0.f, 0.f};

  __syncthreads();   // sAvg zero visible before epilogue (and before any BAR use)

#define STAGEB(buf, kb)                                                         \
  do {                                                                          \
    char* lb = sBbuf + (buf) * 20480 + wid * 5120;                              \
    const ushort_t* bs = bSrc0 + (kb);                                          \
    GLDS16(bs,             lb);                                                 \
    GLDS16(bs + 16 * H_,   lb + 1024);                                          \
    GLDS16(bs + 32 * H_,   lb + 2048);                                          \
    GLDS16(bs + 48 * H_,   lb + 3072);                                          \
    GLDS16(bs + 64 * H_,   lb + 4096);                                          \
  } while (0)

  // prologue: B(0) + x(0).  queue: [B0 x5, x0 x4]
  STAGEB(0, 0);
  f32x4 xa0 = *reinterpret_cast<const f32x4*>(xr0);
  f32x4 xa1 = *reinterpret_cast<const f32x4*>(xr0 + 4);
  f32x4 xb0 = *reinterpret_cast<const f32x4*>(xr1);
  f32x4 xb1 = *reinterpret_cast<const f32x4*>(xr1 + 4);

  const int swzB = (lo >> 1) & 3;

  // ---- GEMM1: logits[128][320] = x_tile[128][1024] @ W_in[g]^T ----
#pragma unroll 1
  for (int ks = 0; ks < 32; ++ks) {
    // stage NEXT B tile first (into dead buffer; prev iter's tail BAR made it safe)
    if (ks < 31) {
      STAGEB((ks + 1) & 1, (ks + 1) * 32);
      // queue: [B(ks) 5, x(ks) 4, B(ks+1) 5] -> complete B(ks)+x(ks), keep B(ks+1) in flight
      asm volatile("s_waitcnt vmcnt(5)" ::: "memory");
    } else {
      asm volatile("s_waitcnt vmcnt(0)" ::: "memory");
    }
    BAR();   // all waves' B(ks) DMAs landed

    bf16x8 af0 = pack8(xa0, xa1);
    bf16x8 af1 = pack8(xb0, xb1);

    if (ks < 31) {   // x regs free after cvt; issue next step's x
      const int ko = (ks + 1) * 32;
      xa0 = *reinterpret_cast<const f32x4*>(xr0 + ko);
      xa1 = *reinterpret_cast<const f32x4*>(xr0 + ko + 4);
      xb0 = *reinterpret_cast<const f32x4*>(xr1 + ko);
      xb1 = *reinterpret_cast<const f32x4*>(xr1 + ko + 4);
    }

    const char* cB = sBbuf + (ks & 1) * 20480;
#pragma unroll
    for (int n = 0; n < 20; ++n) {
      const int v = n * 16 + lo;
      bf16x8 bf = *reinterpret_cast<const bf16x8*>(cB + v * 64 + ((hi ^ swzB) * 16));
      acc[0][n] = __builtin_amdgcn_mfma_f32_16x16x32_bf16(af0, bf, acc[0][n], 0, 0, 0);
      acc[1][n] = __builtin_amdgcn_mfma_f32_16x16x32_bf16(af1, bf, acc[1][n], 0, 0, 0);
    }
    LGKM0();   // my frag reads drained
    BAR();     // all waves done with buf (ks&1) -> reusable next iter
  }
#undef STAGEB

  // ---- epilogue: gumbel softmax (wave-local rows), avg_probs, GEMM2 ----
  float bias[20];
#pragma unroll
  for (int n = 0; n < 20; ++n) bias[n] = b_in[g * 320 + n * 16 + lo];

#pragma unroll
  for (int mrep = 0; mrep < 2; ++mrep) {
#pragma unroll
    for (int j = 0; j < 4; ++j) {
      const int trow = row0 + wm * 32 + mrep * 16 + hi * 4 + j;
      const float* up = gum + ((size_t)trow * G_ + g) * V_;
      float zmax = -3.0e38f;
#pragma unroll
      for (int n = 0; n < 20; ++n) {
        float u = up[n * 16 + lo];
        float gv = -__logf(-__logf(u));
        float z = acc[mrep][n][j] + bias[n] + gv;
        acc[mrep][n][j] = z;
        zmax = fmaxf(zmax, z);
      }
#pragma unroll
      for (int mk = 1; mk <= 8; mk <<= 1) zmax = fmaxf(zmax, __shfl_xor(zmax, mk));
      float s = 0.f;
#pragma unroll
      for (int n = 0; n < 20; ++n) {
        float p = __expf(acc[mrep][n][j] - zmax);
        acc[mrep][n][j] = p;
        s += p;
      }
#pragma unroll
      for (int mk = 1; mk <= 8; mk <<= 1) s += __shfl_xor(s, mk);
      float inv = 1.f / s;
#pragma unroll
      for (int n = 0; n < 20; ++n) acc[mrep][n][j] *= inv;
    }
    // avg_probs accumulation (sum over this wave's 16 rows) -> LDS
#pragma unroll
    for (int n = 0; n < 20; ++n) {
      float cs = acc[mrep][n][0] + acc[mrep][n][1] + acc[mrep][n][2] + acc[mrep][n][3];
      cs += __shfl_xor(cs, 16);
      cs += __shfl_xor(cs, 32);
      if (hi == 0) atomicAdd(&sAvg[n * 16 + lo], cs);
    }
    // probs -> LDS bf16 (pair-packed, wave-local region; 640B rows, XOR-swizzled)
#pragma unroll
    for (int n = 0; n < 20; ++n) {
#pragma unroll
      for (int j = 0; j < 4; ++j) {
        float v = acc[mrep][n][j];
        float pv = __shfl_xor(v, 1);
        if ((lane & 1) == 0) {
          uint_t w = (uint_t)cvt_bf16(v) | ((uint_t)cvt_bf16(pv) << 16);
          int prow = wm * 16 + hi * 4 + j;
          int byte = prow * 640 + (((n * 16 + lo) * 2) ^ ((prow & 7) << 4));
          *reinterpret_cast<uint_t*>(sP + byte) = w;
        }
      }
    }
    LGKM0();
    // GEMM2: qmid[16][128] = P[16][320] @ codebook[g]  (wave reads only its own writes)
    f32x4 acc2[8];
#pragma unroll
    for (int n = 0; n < 8; ++n) acc2[n] = (f32x4){0.f, 0.f, 0.f, 0.f};
#pragma unroll
    for (int kk = 0; kk < 10; ++kk) {
      int prow = wm * 16 + lo;
      int byte = prow * 640 + ((kk * 64 + hi * 16) ^ ((prow & 7) << 4));
      bf16x8 ap = *reinterpret_cast<const bf16x8*>(sP + byte);
#pragma unroll
      for (int n = 0; n < 8; ++n) {
        bf16x8 bc = *reinterpret_cast<const bf16x8*>(cbp + ((size_t)((g * 10 + kk) * 8 + n) * 64 + lane) * 8);
        acc2[n] = __builtin_amdgcn_mfma_f32_16x16x32_bf16(ap, bc, acc2[n], 0, 0, 0);
      }
    }
    // write qmid bf16 (pair-packed u32 stores)
#pragma unroll
    for (int n = 0; n < 8; ++n) {
#pragma unroll
      for (int j = 0; j < 4; ++j) {
        float v = acc2[n][j];
        float pv = __shfl_xor(v, 1);
        if ((lane & 1) == 0) {
          uint_t w = (uint_t)cvt_bf16(v) | ((uint_t)cvt_bf16(pv) << 16);
          int trow = row0 + wm * 32 + mrep * 16 + hi * 4 + j;
          *reinterpret_cast<uint_t*>(qmid + (size_t)trow * GD + g * 128 + n * 16 + lo) = w;
        }
      }
    }
  }
  __syncthreads();
  for (int i = tid; i < V_; i += 256) atomicAdd(&avg_g[g * 320 + i], sAvg[i]);
}

// ---------------- kernel B: q = qmid @ W_out^T + b_out, commit loss, fused finalize ----------------
__global__ __launch_bounds__(512, 2) void pq_kB(
    const ushort_t* __restrict__ qmid, const ushort_t* __restrict__ woutb,
    const float* __restrict__ b_out, const float* __restrict__ x,
    float* __restrict__ out, float* __restrict__ closs,
    const float* __restrict__ avg_g, uint_t* __restrict__ counter) {
  __shared__ char smem[49152 + 64];
  __shared__ int sLast;
  char* sA = smem;            // [128][64] bf16 swizzled
  char* sB = smem + 16384;    // [256][64] bf16 swizzled
  float* sRed = (float*)(smem + 49152);

  const int tid = threadIdx.x;
  const int lane = tid & 63;
  const int wid = tid >> 6;
  const int wm = wid >> 2;    // 0..1
  const int wn = wid & 3;     // 0..3
  const int lo = lane & 15, hi = lane >> 4;
  const int tm = blockIdx.x >> 2;
  const int tn = blockIdx.x & 3;
  const int row0 = tm * 128;
  const int col0 = tn * 256;

  f32x4 acc[4][4];
#pragma unroll
  for (int mr = 0; mr < 4; ++mr)
#pragma unroll
    for (int nr = 0; nr < 4; ++nr) acc[mr][nr] = (f32x4){0.f, 0.f, 0.f, 0.f};

  for (int ks = 0; ks < 4; ++ks) {
    const int kb = ks * 64;
#pragma unroll
    for (int u = 0; u < 2; ++u) {
      int s = u * 512 + tid;
      int r = s >> 3, c = s & 7;
      uint4 wv = *reinterpret_cast<const uint4*>(qmid + (size_t)(row0 + r) * GD + kb + c * 8);
      int byte = (r * 128 + c * 16) ^ ((r & 7) << 4);
      *reinterpret_cast<uint4*>(sA + byte) = wv;
    }
#pragma unroll
    for (int u = 0; u < 4; ++u) {
      int s = u * 512 + tid;
      int r = s >> 3, c = s & 7;
      uint4 wv = *reinterpret_cast<const uint4*>(woutb + (size_t)(col0 + r) * GD + kb + c * 8);
      int byte = (r * 128 + c * 16) ^ ((r & 7) << 4);
      *reinterpret_cast<uint4*>(sB + byte) = wv;
    }
    __syncthreads();
#pragma unroll
    for (int kk = 0; kk < 2; ++kk) {
      bf16x8 af[4], bf[4];
#pragma unroll
      for (int mr = 0; mr < 4; ++mr) {
        int row = wm * 64 + mr * 16 + lo;
        int byte = (row * 128 + kk * 64 + hi * 16) ^ ((row & 7) << 4);
        af[mr] = *reinterpret_cast<const bf16x8*>(sA + byte);
      }
#pragma unroll
      for (int nr = 0; nr < 4; ++nr) {
        int col = wn * 64 + nr * 16 + lo;
        int byte = (col * 128 + kk * 64 + hi * 16) ^ ((col & 7) << 4);
        bf[nr] = *reinterpret_cast<const bf16x8*>(sB + byte);
      }
#pragma unroll
      for (int mr = 0; mr < 4; ++mr)
#pragma unroll
        for (int nr = 0; nr < 4; ++nr)
          acc[mr][nr] = __builtin_amdgcn_mfma_f32_16x16x32_bf16(af[mr], bf[nr], acc[mr][nr], 0, 0, 0);
    }
    __syncthreads();
  }
  // epilogue: bias, store q, commit loss
  float bias[4];
#pragma unroll
  for (int nr = 0; nr < 4; ++nr) bias[nr] = b_out[col0 + wn * 64 + nr * 16 + lo];
  float csum = 0.f;
#pragma unroll
  for (int mr = 0; mr < 4; ++mr)
#pragma unroll
    for (int nr = 0; nr < 4; ++nr)
#pragma unroll
      for (int j = 0; j < 4; ++j) {
        int row = row0 + wm * 64 + mr * 16 + hi * 4 + j;
        int col = col0 + wn * 64 + nr * 16 + lo;
        float q = acc[mr][nr][j] + bias[nr];
        out[(size_t)row * H_ + col] = q;
        float d = x[(size_t)row * H_ + col] - q;
        csum += d * d;
      }
#pragma unroll
  for (int mk = 1; mk <= 32; mk <<= 1) csum += __shfl_xor(csum, mk);
  if (lane == 0) sRed[wid] = csum;
  __syncthreads();
  if (tid == 0) {
    float t = 0.f;
    for (int w = 0; w < 8; ++w) t += sRed[w];
    atomicAdd(closs, t);
    __threadfence();
    uint_t c = atomicAdd(counter, 1u);
    sLast = (c == 1023u) ? 1 : 0;
  }
  __syncthreads();
  // last block finalizes perplexity + commit loss
  if (sLast && tid < 64) {
    float a0 = 0.f, a1 = 0.f;
    for (int v = tid; v < V_; v += 64) {
      float p0 = avg_g[v] * (1.f / (float)NT);
      a0 += p0 * __logf(p0 + 1e-9f);
      float p1 = avg_g[V_ + v] * (1.f / (float)NT);
      a1 += p1 * __logf(p1 + 1e-9f);
    }
#pragma unroll
    for (int mk = 1; mk <= 32; mk <<= 1) { a0 += __shfl_xor(a0, mk); a1 += __shfl_xor(a1, mk); }
    if (tid == 0) {
      float cl = atomicAdd(closs, 0.0f);   // coherent read of accumulated value
      out[(size_t)NT * H_]     = 0.5f * (__expf(-a0) + __expf(-a1));
      out[(size_t)NT * H_ + 1] = cl * (1.f / ((float)NT * (float)H_));
    }
  }
}

extern "C" void kernel_launch(void* const* d_in, const int* in_sizes, int n_in,
                              void* d_out, int out_size, void* d_ws, size_t ws_size,
                              hipStream_t stream) {
  const float* x     = (const float*)d_in[0];
  const float* W_in  = (const float*)d_in[1];
  const float* b_in  = (const float*)d_in[2];
  const float* cb    = (const float*)d_in[3];
  const float* W_out = (const float*)d_in[4];
  const float* b_out = (const float*)d_in[5];
  const float* gum   = (const float*)d_in[6];
  float* out = (float*)d_out;

  char* ws = (char*)d_ws;
  ushort_t* winb  = (ushort_t*)ws;                 // 640*1024*2   = 1,310,720 B
  ushort_t* woutb = (ushort_t*)(ws + 1310720);     // 1024*256*2   =   524,288 B
  ushort_t* cbp   = (ushort_t*)(ws + 1835008);     // 81920*2      =   163,840 B
  float*    avg_g = (float*)(ws + 1998848);        // 640*4        =     2,560 B
  float*    closs = (float*)(ws + 2001408);        // 4 B
  uint_t*   cnt   = (uint_t*)(ws + 2001472);       // 4 B
  ushort_t* qmid  = (ushort_t*)(ws + 2001920);     // 32768*256*2  = 16,777,216 B

  pq_prep<<<3907, 256, 0, stream>>>(W_in, W_out, cb, winb, woutb, cbp, avg_g, closs, cnt);
  pq_kA<<<512, 256, 0, stream>>>(x, b_in, gum, winb, cbp, qmid, avg_g);
  pq_kB<<<1024, 512, 0, stream>>>(qmid, woutb, b_out, x, out, closs, avg_g, cnt);
}